// Round 5
// baseline (1959.045 us; speedup 1.0000x reference)
//
#include <hip/hip_runtime.h>
#include <hip/hip_cooperative_groups.h>

namespace cg = cooperative_groups;

#define CHUNK 400
#define LWIN 50
#define JUMP 8
#define NCH 128
#define BCH 128
#define HCH 512
#define NBLK 14
#define BUF 516
#define SHIFT 508
#define EPSV 1e-8f
#define NWG 65
#define FR 8

__device__ __forceinline__ void loadw4(float4 (&w)[32], const float* p_) {
    const float4* p = (const float4*)p_;
    #pragma unroll
    for (int j = 0; j < 32; ++j) w[j] = p[j];
}

// stage1: yout[t0..t0+nf) = cLN(PReLU(w1 @ xs)); w1 row pre-staged in wreg
__device__ __forceinline__ void stage1_core(
    int tid, int lane, int wid, int t0, int nf,
    const float4 (&wreg)[32], float aPr,
    const float* __restrict__ gv, const float* __restrict__ bv,
    float* __restrict__ yout, float* redf, float* statsf, const float* xsv)
{
    const float4* xv = (const float4*)xsv;
    float acc[FR] = {};
    #pragma unroll
    for (int c4 = 0; c4 < 32; ++c4) {
        float4 w = wreg[c4];
        #pragma unroll
        for (int f = 0; f < FR; ++f) {
            float4 x = xv[f * 32 + c4];
            acc[f] += w.x * x.x + w.y * x.y + w.z * x.z + w.w * x.w;
        }
    }
    #pragma unroll
    for (int f = 0; f < FR; ++f) acc[f] = acc[f] >= 0.f ? acc[f] : aPr * acc[f];
    #pragma unroll
    for (int f = 0; f < FR; ++f) {
        if (f < nf) {
            float s = acc[f], q = acc[f] * acc[f];
            #pragma unroll
            for (int o = 32; o; o >>= 1) { s += __shfl_xor(s, o); q += __shfl_xor(q, o); }
            if (lane == 0) { redf[(wid * FR + f) * 2] = s; redf[(wid * FR + f) * 2 + 1] = q; }
        }
    }
    __syncthreads();
    if (tid < nf) {
        float s = 0.f, q = 0.f;
        #pragma unroll
        for (int w = 0; w < 8; ++w) { s += redf[(w * FR + tid) * 2]; q += redf[(w * FR + tid) * 2 + 1]; }
        float mean = s * (1.f / HCH);
        float var = q * (1.f / HCH) - mean * mean;
        statsf[tid * 2] = mean; statsf[tid * 2 + 1] = rsqrtf(var + EPSV);
    }
    __syncthreads();
    float gg = gv[tid], bb = bv[tid];
    #pragma unroll
    for (int f = 0; f < FR; ++f)
        if (f < nf)
            yout[(t0 + f) * HCH + tid] = gg * (acc[f] - statsf[f * 2]) * statsf[f * 2 + 1] + bb;
}

__global__ __launch_bounds__(512, 1) void k_fused(
    const float* __restrict__ mixture, const float* __restrict__ inEnc,
    const float* __restrict__ inLn, const float* __restrict__ Wenc,
    const float* __restrict__ lng, const float* __restrict__ lnb,
    const float* __restrict__ Wbn, const float* __restrict__ w1,
    const float* __restrict__ p1, const float* __restrict__ g1,
    const float* __restrict__ b1, const float* __restrict__ dwc,
    const float* __restrict__ p2, const float* __restrict__ g2,
    const float* __restrict__ b2, const float* __restrict__ w2,
    const float* __restrict__ Wmask, const float* __restrict__ Wdec,
    float* __restrict__ est, float* __restrict__ outEnc, float* __restrict__ outLn,
    float* __restrict__ xA, float* __restrict__ xB,
    float* __restrict__ y1nA, float* __restrict__ y1nB)
{
    cg::grid_group grid = cg::this_grid();
    __shared__ float xs[FR * BCH];      // stage1 input frames / final-x for mask
    __shared__ float ys[FR * 528];      // stage2 normalized; front scratch; mask sw
    __shared__ float encs[FR * NCH];    // WG0 front scratch
    __shared__ float redf[8 * FR * 2];
    __shared__ float statsf[FR * 2];

    const int wg = blockIdx.x;
    const int tid = threadIdx.x;
    const int lane = tid & 63, wid = tid >> 6;
    const int c = tid >> 2, p = tid & 3;
    float4 wreg[32];                    // union: w1 row, then w2 row, alternating

    // ================= Phase F: front (WG0) | buffer copies (WGs 1..64) ======
    if (wg == 0) {
        #pragma unroll
        for (int k = 0; k < 2; ++k) {
            int o = tid + k * 512;
            int cc = o >> 3, f = o & 7;
            const float* w = Wenc + cc * 100;
            const float* m = mixture + f * LWIN;
            float e = 0.f;
            #pragma unroll 10
            for (int l = 0; l < LWIN; ++l) e += m[l] * w[l] + m[CHUNK + l] * w[LWIN + l];
            e = fmaxf(e, 0.f);
            encs[f * NCH + cc] = e;
            outEnc[cc * BUF + SHIFT + f] = e;
        }
        __syncthreads();
        {   // cLN over channels: wave wid handles frame wid
            float v0 = encs[wid * NCH + lane], v1 = encs[wid * NCH + 64 + lane];
            float s = v0 + v1, q = v0 * v0 + v1 * v1;
            #pragma unroll
            for (int o = 32; o; o >>= 1) { s += __shfl_xor(s, o); q += __shfl_xor(q, o); }
            float mean = s * (1.f / NCH);
            float var = q * (1.f / NCH) - mean * mean;
            float r = rsqrtf(var + EPSV);
            ys[wid * NCH + lane] = lng[lane] * (v0 - mean) * r + lnb[lane];
            ys[wid * NCH + 64 + lane] = lng[64 + lane] * (v1 - mean) * r + lnb[64 + lane];
        }
        __syncthreads();
        #pragma unroll
        for (int k = 0; k < 2; ++k) {   // bottleneck 1x1
            int o = tid + k * 512;
            int b = o & 127, f = o >> 7;
            float acc = 0.f;
            const float4* wr = (const float4*)(Wbn + b * NCH);
            const float4* nv = (const float4*)(ys + f * NCH);
            #pragma unroll
            for (int j4 = 0; j4 < 32; ++j4) {
                float4 w = wr[j4]; float4 x = nv[j4];
                acc += w.x * x.x + w.y * x.y + w.z * x.z + w.w * x.w;
            }
            outLn[b * BUF + SHIFT + f] = acc;
            xA[(SHIFT + f) * BCH + b] = acc;
        }
    } else {
        int c0 = (wg - 1) * 2;
        #pragma unroll
        for (int cc = 0; cc < 2; ++cc) {
            int ch = c0 + cc;
            if (tid < SHIFT) {
                outEnc[ch * BUF + tid] = inEnc[ch * BUF + tid + JUMP];
                float v = inLn[ch * BUF + tid + JUMP];
                outLn[ch * BUF + tid] = v;
                xA[tid * BCH + ch] = v;
            }
        }
    }
    loadw4(wreg, w1 + (size_t)tid * BCH);       // prefetch w1(0), lands during sync
    grid.sync();

    // ================= stage1 of block 0 =====================================
    int T = BUF;
    {
        int FPW = (T + NWG - 1) / NWG;          // 8
        int t0 = wg * FPW;
        if (t0 < T) {
            int nf = min(FPW, T - t0);
            #pragma unroll
            for (int k = 0; k < 2; ++k) {
                int o = tid + k * 512;
                xs[o] = (o < nf * BCH) ? xA[t0 * BCH + o] : 0.f;
            }
            __syncthreads();
            stage1_core(tid, lane, wid, t0, nf, wreg, p1[0], g1, b1, y1nA, redf, statsf, xs);
        }
    }
    loadw4(wreg, w2 + (size_t)c * HCH + p * 128);  // prefetch w2(0), lands during sync
    grid.sync();

    // ================= fused stage2(i) + stage1(i+1) =========================
    const float* xin = xA;  float* xout = xB;
    const float* ycur = y1nA; float* ynext = y1nB;
    for (int i = 0; i < NBLK; ++i) {
        int d = 1 << (i % 7);
        int Tout = T - 2 * d;
        int FPW = (Tout + NWG - 1) / NWG;
        int t0 = wg * FPW;
        bool act = t0 < Tout;           // WG-uniform; may toggle across i (FPW shrinks)
        int nf = act ? min(FPW, Tout - t0) : 0;
        float acc2[FR] = {};
        if (act) {
            const float* dwb = dwc + (size_t)i * HCH * 3 + tid * 3;
            float dw0 = dwb[0], dw1 = dwb[1], dw2 = dwb[2];
            float a2 = p2[i];
            float resv[FR];
            #pragma unroll
            for (int f = 0; f < FR; ++f)
                resv[f] = (f < nf && p == 0) ? xin[(t0 + f + 2 * d) * BCH + c] : 0.f;
            // ---- depthwise conv + PReLU ----
            float yv[FR];
            #pragma unroll
            for (int f = 0; f < FR; ++f) {
                if (f < nf) {
                    int t = t0 + f;
                    float v = dw0 * ycur[t * HCH + tid] + dw1 * ycur[(t + d) * HCH + tid]
                            + dw2 * ycur[(t + 2 * d) * HCH + tid];
                    yv[f] = v >= 0.f ? v : a2 * v;
                } else yv[f] = 0.f;
            }
            // ---- cLN over H ----
            #pragma unroll
            for (int f = 0; f < FR; ++f) {
                if (f < nf) {
                    float s = yv[f], q = yv[f] * yv[f];
                    #pragma unroll
                    for (int o = 32; o; o >>= 1) { s += __shfl_xor(s, o); q += __shfl_xor(q, o); }
                    if (lane == 0) { redf[(wid * FR + f) * 2] = s; redf[(wid * FR + f) * 2 + 1] = q; }
                }
            }
            __syncthreads();
            if (tid < nf) {
                float s = 0.f, q = 0.f;
                #pragma unroll
                for (int w = 0; w < 8; ++w) { s += redf[(w * FR + tid) * 2]; q += redf[(w * FR + tid) * 2 + 1]; }
                float mean = s * (1.f / HCH);
                float var = q * (1.f / HCH) - mean * mean;
                statsf[tid * 2] = mean; statsf[tid * 2 + 1] = rsqrtf(var + EPSV);
            }
            __syncthreads();
            {
                float gg = g2[i * HCH + tid], bb = b2[i * HCH + tid];
                int pidx = (tid >> 7) * 132 + (tid & 127);
                #pragma unroll
                for (int f = 0; f < FR; ++f)
                    if (f < nf)
                        ys[f * 528 + pidx] = gg * (yv[f] - statsf[f * 2]) * statsf[f * 2 + 1] + bb;
            }
            __syncthreads();
            // ---- w2 GEMM (K split by 4, wreg holds w2 rows) ----
            #pragma unroll
            for (int j4 = 0; j4 < 32; ++j4) {
                float4 w = wreg[j4];
                #pragma unroll
                for (int f = 0; f < FR; ++f) {
                    float4 x = *(const float4*)&ys[f * 528 + p * 132 + j4 * 4];
                    acc2[f] += w.x * x.x + w.y * x.y + w.z * x.z + w.w * x.w;
                }
            }
            #pragma unroll
            for (int f = 0; f < FR; ++f) {
                acc2[f] += __shfl_xor(acc2[f], 1);
                acc2[f] += __shfl_xor(acc2[f], 2);
            }
            if (p == 0) {
                #pragma unroll
                for (int f = 0; f < FR; ++f) {
                    if (f < nf) {
                        float xv2 = resv[f] + acc2[f];
                        xout[(t0 + f) * BCH + c] = xv2;
                        xs[f * BCH + c] = xv2;
                    }
                }
            }
        }
        // UNCONDITIONAL w1(i+1) prefetch (inactive WGs may reactivate later)
        if (i < NBLK - 1) loadw4(wreg, w1 + (size_t)(i + 1) * HCH * BCH + (size_t)tid * BCH);
        if (act) {
            __syncthreads();
            if (i < NBLK - 1) {
                stage1_core(tid, lane, wid, t0, nf, wreg, p1[i + 1],
                            g1 + (i + 1) * HCH, b1 + (i + 1) * HCH, ynext, redf, statsf, xs);
            } else {
                // ---- mask conv + ReLU + mask encoder + decoder (nf==1 here) ----
                float m = 0.f;
                const float4* wm = (const float4*)(Wmask + c * BCH + p * 32);
                const float4* xv2 = (const float4*)(xs + p * 32);
                #pragma unroll
                for (int j4 = 0; j4 < 8; ++j4) {
                    float4 w = wm[j4]; float4 x = xv2[j4];
                    m += w.x * x.x + w.y * x.y + w.z * x.z + w.w * x.w;
                }
                m += __shfl_xor(m, 1);
                m += __shfl_xor(m, 2);
                if (p == 0)
                    ys[c] = fmaxf(m, 0.f) * outEnc[c * BUF + SHIFT + t0];
                __syncthreads();
                if (tid < 4 * LWIN) {
                    int l = tid >> 2;
                    float e = 0.f;
                    const float4* wd = (const float4*)(Wdec + l * NCH + p * 32);
                    const float4* sv = (const float4*)(ys + p * 32);
                    #pragma unroll
                    for (int j4 = 0; j4 < 8; ++j4) {
                        float4 w = wd[j4]; float4 x = sv[j4];
                        e += w.x * x.x + w.y * x.y + w.z * x.z + w.w * x.w;
                    }
                    e += __shfl_xor(e, 1);
                    e += __shfl_xor(e, 2);
                    if (p == 0) est[t0 * LWIN + l] = e;
                }
            }
        }
        // UNCONDITIONAL w2(i+1) prefetch, lands during the grid sync
        if (i < NBLK - 1) {
            loadw4(wreg, w2 + (size_t)(i + 1) * BCH * HCH + (size_t)c * HCH + p * 128);
            grid.sync();
        }
        T = Tout;
        const float* tf = xin; xin = xout; xout = (float*)tf;
        const float* ty = ycur; ycur = ynext; ynext = (float*)ty;
    }
}

extern "C" void kernel_launch(void* const* d_in, const int* in_sizes, int n_in,
                              void* d_out, int out_size, void* d_ws, size_t ws_size,
                              hipStream_t stream) {
    const float* mixture = (const float*)d_in[0];
    const float* inEnc   = (const float*)d_in[1];
    const float* inLn    = (const float*)d_in[2];
    const float* Wenc    = (const float*)d_in[3];
    const float* lng     = (const float*)d_in[4];
    const float* lnb     = (const float*)d_in[5];
    const float* Wbn     = (const float*)d_in[6];
    const float* w1      = (const float*)d_in[7];
    const float* p1      = (const float*)d_in[8];
    const float* g1      = (const float*)d_in[9];
    const float* b1      = (const float*)d_in[10];
    const float* dwc     = (const float*)d_in[11];
    const float* p2      = (const float*)d_in[12];
    const float* g2      = (const float*)d_in[13];
    const float* b2      = (const float*)d_in[14];
    const float* w2      = (const float*)d_in[15];
    const float* Wmask   = (const float*)d_in[16];
    const float* Wdec    = (const float*)d_in[17];

    float* est    = (float*)d_out;
    float* outEnc = est + CHUNK;
    float* outLn  = outEnc + NCH * BUF;

    float* ws   = (float*)d_ws;
    float* xA   = ws;                      // 66048
    float* xB   = xA + BUF * BCH;          // 66048
    float* y1nA = xB + BUF * BCH;          // 264192
    float* y1nB = y1nA + BUF * HCH;        // 264192

    void* args[] = { &mixture, &inEnc, &inLn, &Wenc, &lng, &lnb, &Wbn, &w1, &p1,
                     &g1, &b1, &dwc, &p2, &g2, &b2, &w2, &Wmask, &Wdec,
                     &est, &outEnc, &outLn, &xA, &xB, &y1nA, &y1nB };
    hipLaunchCooperativeKernel((const void*)k_fused, dim3(NWG), dim3(512),
                               (void**)args, 0, stream);
}

// Round 6
// 1927.520 us; speedup vs baseline: 1.0164x; 1.0164x over previous
//
#include <hip/hip_runtime.h>

#define CHUNK 400
#define LWIN 50
#define JUMP 8
#define NCH 128
#define BCH 128
#define HCH 512
#define NBLK 14
#define BUF 516
#define SHIFT 508
#define EPSV 1e-8f
#define NWG 65
#define FR 8

__device__ __forceinline__ void gsync(unsigned* bar, int slot, int tid) {
    __syncthreads();                       // drains vmcnt: all WG writes at L2
    if (tid == 0) {
        unsigned* p = bar + slot;
        __hip_atomic_fetch_add(p, 1u, __ATOMIC_RELEASE, __HIP_MEMORY_SCOPE_AGENT);
        while (__hip_atomic_load(p, __ATOMIC_RELAXED, __HIP_MEMORY_SCOPE_AGENT) < NWG)
            __builtin_amdgcn_s_sleep(8);
        (void)__hip_atomic_load(p, __ATOMIC_ACQUIRE, __HIP_MEMORY_SCOPE_AGENT);
    }
    __syncthreads();
}

__device__ __forceinline__ void loadw4(float4 (&w)[32], const float* p_) {
    const float4* p = (const float4*)p_;
    #pragma unroll
    for (int j = 0; j < 32; ++j) w[j] = p[j];
}

// stage1: yout[t0..t0+nf) = cLN(PReLU(w1 @ xs)); w1 row pre-staged in wreg
__device__ __forceinline__ void stage1_core(
    int tid, int lane, int wid, int t0, int nf,
    const float4 (&wreg)[32], float aPr,
    const float* __restrict__ gv, const float* __restrict__ bv,
    float* __restrict__ yout, float* redf, float* statsf, const float* xsv)
{
    const float4* xv = (const float4*)xsv;
    float acc[FR] = {};
    #pragma unroll
    for (int c4 = 0; c4 < 32; ++c4) {
        float4 w = wreg[c4];
        #pragma unroll
        for (int f = 0; f < FR; ++f) {
            float4 x = xv[f * 32 + c4];
            acc[f] += w.x * x.x + w.y * x.y + w.z * x.z + w.w * x.w;
        }
    }
    #pragma unroll
    for (int f = 0; f < FR; ++f) acc[f] = acc[f] >= 0.f ? acc[f] : aPr * acc[f];
    #pragma unroll
    for (int f = 0; f < FR; ++f) {
        if (f < nf) {
            float s = acc[f], q = acc[f] * acc[f];
            #pragma unroll
            for (int o = 32; o; o >>= 1) { s += __shfl_xor(s, o); q += __shfl_xor(q, o); }
            if (lane == 0) { redf[(wid * FR + f) * 2] = s; redf[(wid * FR + f) * 2 + 1] = q; }
        }
    }
    __syncthreads();
    if (tid < nf) {
        float s = 0.f, q = 0.f;
        #pragma unroll
        for (int w = 0; w < 8; ++w) { s += redf[(w * FR + tid) * 2]; q += redf[(w * FR + tid) * 2 + 1]; }
        float mean = s * (1.f / HCH);
        float var = q * (1.f / HCH) - mean * mean;
        statsf[tid * 2] = mean; statsf[tid * 2 + 1] = rsqrtf(var + EPSV);
    }
    __syncthreads();
    float gg = gv[tid], bb = bv[tid];
    #pragma unroll
    for (int f = 0; f < FR; ++f)
        if (f < nf)
            yout[(t0 + f) * HCH + tid] = gg * (acc[f] - statsf[f * 2]) * statsf[f * 2 + 1] + bb;
}

__global__ __launch_bounds__(512, 1) void k_fused(
    const float* __restrict__ mixture, const float* __restrict__ inEnc,
    const float* __restrict__ inLn, const float* __restrict__ Wenc,
    const float* __restrict__ lng, const float* __restrict__ lnb,
    const float* __restrict__ Wbn, const float* __restrict__ w1,
    const float* __restrict__ p1, const float* __restrict__ g1,
    const float* __restrict__ b1, const float* __restrict__ dwc,
    const float* __restrict__ p2, const float* __restrict__ g2,
    const float* __restrict__ b2, const float* __restrict__ w2,
    const float* __restrict__ Wmask, const float* __restrict__ Wdec,
    float* __restrict__ est, float* __restrict__ outEnc, float* __restrict__ outLn,
    unsigned* __restrict__ bar,
    float* __restrict__ xA, float* __restrict__ xB,
    float* __restrict__ y1nA, float* __restrict__ y1nB)
{
    __shared__ float xs[FR * BCH];      // stage1 input frames / final-x for mask
    __shared__ float ys[FR * 528];      // stage2 normalized; front scratch; mask sw
    __shared__ float encs[FR * NCH];    // WG0 front scratch
    __shared__ float redf[8 * FR * 2];
    __shared__ float statsf[FR * 2];

    const int wg = blockIdx.x;
    const int tid = threadIdx.x;
    const int lane = tid & 63, wid = tid >> 6;
    const int c = tid >> 2, p = tid & 3;
    float4 wreg[32];                    // union: w1 row, then w2 row, alternating

    // ================= Phase F: front (WG0) | buffer copies (WGs 1..64) ======
    if (wg == 0) {
        #pragma unroll
        for (int k = 0; k < 2; ++k) {
            int o = tid + k * 512;
            int cc = o >> 3, f = o & 7;
            const float* w = Wenc + cc * 100;
            const float* m = mixture + f * LWIN;
            float e = 0.f;
            #pragma unroll 10
            for (int l = 0; l < LWIN; ++l) e += m[l] * w[l] + m[CHUNK + l] * w[LWIN + l];
            e = fmaxf(e, 0.f);
            encs[f * NCH + cc] = e;
            outEnc[cc * BUF + SHIFT + f] = e;
        }
        __syncthreads();
        {   // cLN over channels: wave wid handles frame wid
            float v0 = encs[wid * NCH + lane], v1 = encs[wid * NCH + 64 + lane];
            float s = v0 + v1, q = v0 * v0 + v1 * v1;
            #pragma unroll
            for (int o = 32; o; o >>= 1) { s += __shfl_xor(s, o); q += __shfl_xor(q, o); }
            float mean = s * (1.f / NCH);
            float var = q * (1.f / NCH) - mean * mean;
            float r = rsqrtf(var + EPSV);
            ys[wid * NCH + lane] = lng[lane] * (v0 - mean) * r + lnb[lane];
            ys[wid * NCH + 64 + lane] = lng[64 + lane] * (v1 - mean) * r + lnb[64 + lane];
        }
        __syncthreads();
        #pragma unroll
        for (int k = 0; k < 2; ++k) {   // bottleneck 1x1
            int o = tid + k * 512;
            int b = o & 127, f = o >> 7;
            float acc = 0.f;
            const float4* wr = (const float4*)(Wbn + b * NCH);
            const float4* nv = (const float4*)(ys + f * NCH);
            #pragma unroll
            for (int j4 = 0; j4 < 32; ++j4) {
                float4 w = wr[j4]; float4 x = nv[j4];
                acc += w.x * x.x + w.y * x.y + w.z * x.z + w.w * x.w;
            }
            outLn[b * BUF + SHIFT + f] = acc;
            xA[(SHIFT + f) * BCH + b] = acc;
        }
    } else {
        int c0 = (wg - 1) * 2;
        #pragma unroll
        for (int cc = 0; cc < 2; ++cc) {
            int ch = c0 + cc;
            if (tid < SHIFT) {
                outEnc[ch * BUF + tid] = inEnc[ch * BUF + tid + JUMP];
                float v = inLn[ch * BUF + tid + JUMP];
                outLn[ch * BUF + tid] = v;
                xA[tid * BCH + ch] = v;
            }
        }
    }
    loadw4(wreg, w1 + (size_t)tid * BCH);       // prefetch w1(0), lands during sync
    gsync(bar, 0, tid);

    // ================= stage1 of block 0 =====================================
    int T = BUF;
    {
        int FPW = (T + NWG - 1) / NWG;          // 8
        int t0 = wg * FPW;
        if (t0 < T) {
            int nf = min(FPW, T - t0);
            #pragma unroll
            for (int k = 0; k < 2; ++k) {
                int o = tid + k * 512;
                xs[o] = (o < nf * BCH) ? xA[t0 * BCH + o] : 0.f;
            }
            __syncthreads();
            stage1_core(tid, lane, wid, t0, nf, wreg, p1[0], g1, b1, y1nA, redf, statsf, xs);
        }
    }
    loadw4(wreg, w2 + (size_t)c * HCH + p * 128);  // prefetch w2(0), lands during sync
    gsync(bar, 1, tid);

    // ================= fused stage2(i) + stage1(i+1) =========================
    const float* xin = xA;  float* xout = xB;
    const float* ycur = y1nA; float* ynext = y1nB;
    for (int i = 0; i < NBLK; ++i) {
        int d = 1 << (i % 7);
        int Tout = T - 2 * d;
        int FPW = (Tout + NWG - 1) / NWG;
        int t0 = wg * FPW;
        bool act = t0 < Tout;           // WG-uniform; may toggle across i (FPW shrinks)
        int nf = act ? min(FPW, Tout - t0) : 0;
        float acc2[FR] = {};
        if (act) {
            const float* dwb = dwc + (size_t)i * HCH * 3 + tid * 3;
            float dw0 = dwb[0], dw1 = dwb[1], dw2 = dwb[2];
            float a2 = p2[i];
            float resv[FR];
            #pragma unroll
            for (int f = 0; f < FR; ++f)
                resv[f] = (f < nf && p == 0) ? xin[(t0 + f + 2 * d) * BCH + c] : 0.f;
            // ---- depthwise conv + PReLU ----
            float yv[FR];
            #pragma unroll
            for (int f = 0; f < FR; ++f) {
                if (f < nf) {
                    int t = t0 + f;
                    float v = dw0 * ycur[t * HCH + tid] + dw1 * ycur[(t + d) * HCH + tid]
                            + dw2 * ycur[(t + 2 * d) * HCH + tid];
                    yv[f] = v >= 0.f ? v : a2 * v;
                } else yv[f] = 0.f;
            }
            // ---- cLN over H ----
            #pragma unroll
            for (int f = 0; f < FR; ++f) {
                if (f < nf) {
                    float s = yv[f], q = yv[f] * yv[f];
                    #pragma unroll
                    for (int o = 32; o; o >>= 1) { s += __shfl_xor(s, o); q += __shfl_xor(q, o); }
                    if (lane == 0) { redf[(wid * FR + f) * 2] = s; redf[(wid * FR + f) * 2 + 1] = q; }
                }
            }
            __syncthreads();
            if (tid < nf) {
                float s = 0.f, q = 0.f;
                #pragma unroll
                for (int w = 0; w < 8; ++w) { s += redf[(w * FR + tid) * 2]; q += redf[(w * FR + tid) * 2 + 1]; }
                float mean = s * (1.f / HCH);
                float var = q * (1.f / HCH) - mean * mean;
                statsf[tid * 2] = mean; statsf[tid * 2 + 1] = rsqrtf(var + EPSV);
            }
            __syncthreads();
            {
                float gg = g2[i * HCH + tid], bb = b2[i * HCH + tid];
                int pidx = (tid >> 7) * 132 + (tid & 127);
                #pragma unroll
                for (int f = 0; f < FR; ++f)
                    if (f < nf)
                        ys[f * 528 + pidx] = gg * (yv[f] - statsf[f * 2]) * statsf[f * 2 + 1] + bb;
            }
            __syncthreads();
            // ---- w2 GEMM (K split by 4, wreg holds w2 rows) ----
            #pragma unroll
            for (int j4 = 0; j4 < 32; ++j4) {
                float4 w = wreg[j4];
                #pragma unroll
                for (int f = 0; f < FR; ++f) {
                    float4 x = *(const float4*)&ys[f * 528 + p * 132 + j4 * 4];
                    acc2[f] += w.x * x.x + w.y * x.y + w.z * x.z + w.w * x.w;
                }
            }
            #pragma unroll
            for (int f = 0; f < FR; ++f) {
                acc2[f] += __shfl_xor(acc2[f], 1);
                acc2[f] += __shfl_xor(acc2[f], 2);
            }
            if (p == 0) {
                #pragma unroll
                for (int f = 0; f < FR; ++f) {
                    if (f < nf) {
                        float xv2 = resv[f] + acc2[f];
                        xout[(t0 + f) * BCH + c] = xv2;
                        xs[f * BCH + c] = xv2;
                    }
                }
            }
        }
        // UNCONDITIONAL w1(i+1) prefetch (inactive WGs may reactivate later)
        if (i < NBLK - 1) loadw4(wreg, w1 + (size_t)(i + 1) * HCH * BCH + (size_t)tid * BCH);
        if (act) {
            __syncthreads();
            if (i < NBLK - 1) {
                stage1_core(tid, lane, wid, t0, nf, wreg, p1[i + 1],
                            g1 + (i + 1) * HCH, b1 + (i + 1) * HCH, ynext, redf, statsf, xs);
            } else {
                // ---- mask conv + ReLU + mask encoder + decoder (nf==1 here) ----
                float m = 0.f;
                const float4* wm = (const float4*)(Wmask + c * BCH + p * 32);
                const float4* xv2 = (const float4*)(xs + p * 32);
                #pragma unroll
                for (int j4 = 0; j4 < 8; ++j4) {
                    float4 w = wm[j4]; float4 x = xv2[j4];
                    m += w.x * x.x + w.y * x.y + w.z * x.z + w.w * x.w;
                }
                m += __shfl_xor(m, 1);
                m += __shfl_xor(m, 2);
                if (p == 0)
                    ys[c] = fmaxf(m, 0.f) * outEnc[c * BUF + SHIFT + t0];
                __syncthreads();
                if (tid < 4 * LWIN) {
                    int l = tid >> 2;
                    float e = 0.f;
                    const float4* wd = (const float4*)(Wdec + l * NCH + p * 32);
                    const float4* sv = (const float4*)(ys + p * 32);
                    #pragma unroll
                    for (int j4 = 0; j4 < 8; ++j4) {
                        float4 w = wd[j4]; float4 x = sv[j4];
                        e += w.x * x.x + w.y * x.y + w.z * x.z + w.w * x.w;
                    }
                    e += __shfl_xor(e, 1);
                    e += __shfl_xor(e, 2);
                    if (p == 0) est[t0 * LWIN + l] = e;
                }
            }
        }
        // UNCONDITIONAL w2(i+1) prefetch, lands during the barrier spin
        if (i < NBLK - 1) {
            loadw4(wreg, w2 + (size_t)(i + 1) * BCH * HCH + (size_t)c * HCH + p * 128);
            gsync(bar, 2 + i, tid);
        }
        T = Tout;
        const float* tf = xin; xin = xout; xout = (float*)tf;
        const float* ty = ycur; ycur = ynext; ynext = (float*)ty;
    }
}

extern "C" void kernel_launch(void* const* d_in, const int* in_sizes, int n_in,
                              void* d_out, int out_size, void* d_ws, size_t ws_size,
                              hipStream_t stream) {
    const float* mixture = (const float*)d_in[0];
    const float* inEnc   = (const float*)d_in[1];
    const float* inLn    = (const float*)d_in[2];
    const float* Wenc    = (const float*)d_in[3];
    const float* lng     = (const float*)d_in[4];
    const float* lnb     = (const float*)d_in[5];
    const float* Wbn     = (const float*)d_in[6];
    const float* w1      = (const float*)d_in[7];
    const float* p1      = (const float*)d_in[8];
    const float* g1      = (const float*)d_in[9];
    const float* b1      = (const float*)d_in[10];
    const float* dwc     = (const float*)d_in[11];
    const float* p2      = (const float*)d_in[12];
    const float* g2      = (const float*)d_in[13];
    const float* b2      = (const float*)d_in[14];
    const float* w2      = (const float*)d_in[15];
    const float* Wmask   = (const float*)d_in[16];
    const float* Wdec    = (const float*)d_in[17];

    float* est    = (float*)d_out;
    float* outEnc = est + CHUNK;
    float* outLn  = outEnc + NCH * BUF;

    unsigned* bar = (unsigned*)d_ws;       // 32 slots (128 B), zeroed every call
    float* xA   = (float*)d_ws + 32;       // 66048
    float* xB   = xA + BUF * BCH;          // 66048
    float* y1nA = xB + BUF * BCH;          // 264192
    float* y1nB = y1nA + BUF * HCH;        // 264192

    hipMemsetAsync(d_ws, 0, 128, stream);

    void* args[] = { &mixture, &inEnc, &inLn, &Wenc, &lng, &lnb, &Wbn, &w1, &p1,
                     &g1, &b1, &dwc, &p2, &g2, &b2, &w2, &Wmask, &Wdec,
                     &est, &outEnc, &outLn, &bar, &xA, &xB, &y1nA, &y1nB };
    hipLaunchCooperativeKernel((const void*)k_fused, dim3(NWG), dim3(512),
                               (void**)args, 0, stream);
}